// Round 12
// baseline (601.227 us; speedup 1.0000x reference)
//
#include <hip/hip_runtime.h>

static constexpr int NN = 50000;   // nodes
static constexpr int NE = 800000;  // edges
static constexpr int D0 = 128;     // in dim
static constexpr int D1 = 256;     // hidden
static constexpr int D2 = 5;       // out

static constexpr int NB  = 512;    // grid blocks; launch_bounds(256,2) => 2/CU
static constexpr int TPB = 256;

// bucketed edge sort: bucket = dst>>8, 256 nodes/bucket
static constexpr int BSZ   = 256;
static constexpr int NBUK  = (NN + BSZ - 1) / BSZ;  // 196
static constexpr int CAP   = 4800;   // per-bucket slab cap (mean 4082, +11 sd)
static constexpr int CB    = 400;    // chunks
static constexpr int CHUNK = 2000;   // edges per chunk (CB*CHUNK == NE)

static constexpr int NTILE = 2 * ((NN + 127) / 128);  // 782 gemm tiles

// LDS arena: peak = P4 sA|sB = 36864 B (sH 34816 aliases it; P1 21120; P2 4096)
static constexpr int SMEM_BYTES = 36864;

using short8  = __attribute__((ext_vector_type(8))) short;
using floatx4 = __attribute__((ext_vector_type(4))) float;

__device__ __forceinline__ unsigned short f2b(float f) {
  union { float f; unsigned u; } v; v.f = f;
  unsigned r = v.u + 0x7fffu + ((v.u >> 16) & 1u);  // RNE
  return (unsigned short)(r >> 16);
}
__device__ __forceinline__ float b2f(unsigned short s) {
  union { unsigned u; float f; } v; v.u = ((unsigned)s) << 16;
  return v.f;
}

// manual grid barrier: all NB blocks are co-resident by occupancy construction.
__device__ __forceinline__ void gbar(int* ctr) {
  __syncthreads();
  if (threadIdx.x == 0) {
    __threadfence();  // release: prior writes visible before arrival
    atomicAdd(ctr, 1);
    long guard = 0;
    while (__hip_atomic_load(ctr, __ATOMIC_ACQUIRE, __HIP_MEMORY_SCOPE_AGENT) <
               NB &&
           ++guard < 100000000L) {
    }
  }
  __syncthreads();
}

__global__ __launch_bounds__(256, 2) void k_all(
    const float* __restrict__ x, const int* __restrict__ src,
    const int* __restrict__ dst, const float* __restrict__ W1l,
    const float* __restrict__ b1l, const float* __restrict__ W1r,
    const float* __restrict__ W2l, const float* __restrict__ b2l,
    const float* __restrict__ W2r, unsigned short* __restrict__ ab,
    unsigned short* __restrict__ wb, unsigned short* __restrict__ w2b,
    float* __restrict__ tt, float* __restrict__ rp, uint2* __restrict__ slab,
    int* __restrict__ gcur, int* __restrict__ cur, float* __restrict__ inv,
    int* __restrict__ esort, int* __restrict__ ctr, float* __restrict__ out) {
  __shared__ __align__(16) char smem[SMEM_BYTES];
  const int t = threadIdx.x;
  const int bx = blockIdx.x;
  const int gid = bx * TPB + t;

  // ================= P0: fp32 -> bf16 converts (grid-stride) =================
  for (int idx = gid; idx < NN * 32; idx += NB * TPB) {
    const int node = idx >> 5, cg4 = idx & 31;
    const float4 v = *(const float4*)(x + (size_t)node * D0 + cg4 * 4);
    ushort4 o;
    o.x = f2b(v.x); o.y = f2b(v.y); o.z = f2b(v.z); o.w = f2b(v.w);
    *(ushort4*)(ab + (size_t)node * 256 + 128 + cg4 * 4) = o;
  }
  for (int idx = gid; idx < 256 * 64; idx += NB * TPB) {
    const int c = idx >> 6, k = (idx & 63) * 4;
    const float* srcp = (k < 128) ? (W1l + (size_t)c * 128 + k)
                                  : (W1r + (size_t)c * 128 + (k - 128));
    const float4 v = *(const float4*)srcp;
    ushort4 o;
    o.x = f2b(v.x); o.y = f2b(v.y); o.z = f2b(v.z); o.w = f2b(v.w);
    *(ushort4*)(wb + (size_t)c * 256 + k) = o;
  }
  if (gid < 1024) {  // w2b[16][256], rows 10..15 zero
    const int n = gid >> 6, k = (gid & 63) * 4;
    float4 v = {0.f, 0.f, 0.f, 0.f};
    if (n < 5) v = *(const float4*)(W2l + (size_t)n * D1 + k);
    else if (n < 10) v = *(const float4*)(W2r + (size_t)(n - 5) * D1 + k);
    ushort4 o;
    o.x = f2b(v.x); o.y = f2b(v.y); o.z = f2b(v.z); o.w = f2b(v.w);
    *(ushort4*)(w2b + (size_t)n * 256 + k) = o;
  }

  // ================= P1: bucketA (proven R9 logic, bucket = dst>>8) ==========
  if (bx < CB) {
    int* hist = (int*)smem;                // 256
    int* ss = hist + 256;                  // 256
    int* bstart = ss + 256;                // 256
    int* hcur = bstart + 256;              // 256
    int* gbase = hcur + 256;               // 256
    uint2* pairs = (uint2*)(gbase + 256);  // 2000  (total 21120 B)
    const int e0 = bx * CHUNK;
    hist[t] = 0;
    __syncthreads();
    for (int j = t; j < CHUNK; j += TPB) atomicAdd(&hist[dst[e0 + j] >> 8], 1);
    __syncthreads();
    ss[t] = hist[t];
    __syncthreads();
    for (int dd = 1; dd < 256; dd <<= 1) {
      const int u = (t >= dd) ? ss[t - dd] : 0;
      __syncthreads();
      ss[t] += u;
      __syncthreads();
    }
    bstart[t] = ss[t] - hist[t];
    hcur[t] = 0;
    gbase[t] = (t < NBUK && hist[t] > 0) ? atomicAdd(&gcur[t], hist[t]) : 0;
    __syncthreads();
    for (int j = t; j < CHUNK; j += TPB) {
      const int s = src[e0 + j], d = dst[e0 + j];
      const int bk = d >> 8;
      const int pos = bstart[bk] + atomicAdd(&hcur[bk], 1);
      pairs[pos] = make_uint2((unsigned)s, (unsigned)d);
    }
    __syncthreads();
    for (int j = t; j < CHUNK; j += TPB) {
      const uint2 pr = pairs[j];
      const int bk = (int)pr.y >> 8;
      slab[(size_t)bk * CAP + gbase[bk] + (j - bstart[bk])] = pr;
    }
  }
  gbar(ctr + 0);

  // ================= P2: bucketBC (proven R9 logic, 256 thr) =================
  if (bx < NBUK) {
    int* bs = (int*)smem;     // 256
    int* cnt = bs + 256;      // 256
    int* s = cnt + 256;       // 256
    int* lcur = s + 256;      // 256  (total 4096 B)
    const int n0 = bx << 8;
    bs[t] = (t < NBUK) ? gcur[t] : 0;
    cnt[t] = 0;
    __syncthreads();
    for (int dd = 1; dd < 256; dd <<= 1) {
      const int u = (t >= dd) ? bs[t - dd] : 0;
      __syncthreads();
      bs[t] += u;
      __syncthreads();
    }
    const int bbase = (bx == 0) ? 0 : bs[bx - 1];
    const int cntE = gcur[bx];
    const uint2* sp = slab + (size_t)bx * CAP;
    for (int j = t; j < cntE; j += TPB) atomicAdd(&cnt[(int)sp[j].y & 255], 1);
    __syncthreads();
    s[t] = cnt[t];
    __syncthreads();
    for (int dd = 1; dd < 256; dd <<= 1) {
      const int u = (t >= dd) ? s[t - dd] : 0;
      __syncthreads();
      s[t] += u;
      __syncthreads();
    }
    const int start = bbase + (s[t] - cnt[t]);
    const int node = n0 + t;
    if (node < NN) {
      cur[node] = start;
      inv[node] = 1.0f / (float)max(cnt[t], 1);
    }
    lcur[t] = start;
    if (bx == 0 && t == 0) cur[NN] = bs[NBUK - 1];
    __syncthreads();
    for (int j = t; j < cntE; j += TPB) {
      const uint2 pr = sp[j];
      const int p = atomicAdd(&lcur[(int)pr.y & 255], 1);
      esort[p] = (int)pr.x;
    }
  }
  gbar(ctr + 1);

  // ================= P3: layer-1 mean aggregate (one wave per node) ==========
  {
    const int lane = t & 63;
    const unsigned short* xb = ab + 128 + lane * 2;
    for (int i = gid >> 6; i < NN; i += (NB * TPB) >> 6) {
      int e = cur[i];
      const int end = cur[i + 1];
      float a0 = 0.f, b0 = 0.f, a1 = 0.f, b1 = 0.f;
      float a2 = 0.f, b2 = 0.f, a3 = 0.f, b3 = 0.f;
      while (e < end && (e & 3)) {
        const unsigned v = *(const unsigned*)(xb + (size_t)esort[e] * 256);
        a0 += b2f((unsigned short)v); b0 += b2f((unsigned short)(v >> 16));
        ++e;
      }
      for (; e + 7 < end; e += 8) {
        const int4 s0 = *(const int4*)(esort + e);
        const int4 s1 = *(const int4*)(esort + e + 4);
        const unsigned v0 = *(const unsigned*)(xb + (size_t)s0.x * 256);
        const unsigned v1 = *(const unsigned*)(xb + (size_t)s0.y * 256);
        const unsigned v2 = *(const unsigned*)(xb + (size_t)s0.z * 256);
        const unsigned v3 = *(const unsigned*)(xb + (size_t)s0.w * 256);
        const unsigned v4 = *(const unsigned*)(xb + (size_t)s1.x * 256);
        const unsigned v5 = *(const unsigned*)(xb + (size_t)s1.y * 256);
        const unsigned v6 = *(const unsigned*)(xb + (size_t)s1.z * 256);
        const unsigned v7 = *(const unsigned*)(xb + (size_t)s1.w * 256);
        a0 += b2f((unsigned short)v0); b0 += b2f((unsigned short)(v0 >> 16));
        a1 += b2f((unsigned short)v1); b1 += b2f((unsigned short)(v1 >> 16));
        a2 += b2f((unsigned short)v2); b2 += b2f((unsigned short)(v2 >> 16));
        a3 += b2f((unsigned short)v3); b3 += b2f((unsigned short)(v3 >> 16));
        a0 += b2f((unsigned short)v4); b0 += b2f((unsigned short)(v4 >> 16));
        a1 += b2f((unsigned short)v5); b1 += b2f((unsigned short)(v5 >> 16));
        a2 += b2f((unsigned short)v6); b2 += b2f((unsigned short)(v6 >> 16));
        a3 += b2f((unsigned short)v7); b3 += b2f((unsigned short)(v7 >> 16));
      }
      if (e + 3 < end) {
        const int4 s0 = *(const int4*)(esort + e);
        const unsigned v0 = *(const unsigned*)(xb + (size_t)s0.x * 256);
        const unsigned v1 = *(const unsigned*)(xb + (size_t)s0.y * 256);
        const unsigned v2 = *(const unsigned*)(xb + (size_t)s0.z * 256);
        const unsigned v3 = *(const unsigned*)(xb + (size_t)s0.w * 256);
        a0 += b2f((unsigned short)v0); b0 += b2f((unsigned short)(v0 >> 16));
        a1 += b2f((unsigned short)v1); b1 += b2f((unsigned short)(v1 >> 16));
        a2 += b2f((unsigned short)v2); b2 += b2f((unsigned short)(v2 >> 16));
        a3 += b2f((unsigned short)v3); b3 += b2f((unsigned short)(v3 >> 16));
        e += 4;
      }
      for (; e < end; ++e) {
        const unsigned v = *(const unsigned*)(xb + (size_t)esort[e] * 256);
        a0 += b2f((unsigned short)v); b0 += b2f((unsigned short)(v >> 16));
      }
      const float sc = inv[i];
      const float sa = (a0 + a1) + (a2 + a3);
      const float sb = (b0 + b1) + (b2 + b3);
      const unsigned o =
          ((unsigned)f2b(sb * sc) << 16) | (unsigned)f2b(sa * sc);
      *(unsigned*)(ab + (size_t)i * 256 + lane * 2) = o;
    }
  }
  gbar(ctr + 2);

  // ================= P4: GEMM1 + fused layer-2 linear (proven R9) ============
  {
    short* sA = (short*)smem;
    short* sB = sA + 128 * 72;
    const int wave = t >> 6, lane = t & 63;
    const int quad = lane >> 4, m16 = lane & 15;
    const int wm = wave & 1, wn = wave >> 1;
    const int lr = t >> 2;
    const int lk = (t & 3) * 8;
    const uint4 zz = make_uint4(0, 0, 0, 0);
    for (int tile = bx; tile < NTILE; tile += NB) {
      const int row0 = (tile >> 1) * 128;
      const int hf = tile & 1;
      const int col0 = hf * 128;
      floatx4 acc[4][4];
#pragma unroll
      for (int a = 0; a < 4; ++a)
#pragma unroll
        for (int b = 0; b < 4; ++b) acc[a][b] = {0.f, 0.f, 0.f, 0.f};
      const int gr0 = row0 + lr, gr1 = row0 + lr + 64;
      const bool ok0 = gr0 < NN, ok1 = gr1 < NN;
      const unsigned short* aptr0 = ab + (size_t)gr0 * 256 + lk;
      const unsigned short* aptr1 = ab + (size_t)gr1 * 256 + lk;
      const unsigned short* bptr0 = wb + (size_t)(col0 + lr) * 256 + lk;
      const unsigned short* bptr1 = wb + (size_t)(col0 + lr + 64) * 256 + lk;
      short* sA0 = &sA[lr * 72 + lk];
      short* sA1 = &sA[(lr + 64) * 72 + lk];
      short* sB0 = &sB[lr * 72 + lk];
      short* sB1 = &sB[(lr + 64) * 72 + lk];
      for (int kk = 0; kk < 256; kk += 64) {
        const uint4 a00 = ok0 ? *(const uint4*)(aptr0 + kk) : zz;
        const uint4 a01 = ok0 ? *(const uint4*)(aptr0 + kk + 32) : zz;
        const uint4 a10 = ok1 ? *(const uint4*)(aptr1 + kk) : zz;
        const uint4 a11 = ok1 ? *(const uint4*)(aptr1 + kk + 32) : zz;
        const uint4 b00 = *(const uint4*)(bptr0 + kk);
        const uint4 b01 = *(const uint4*)(bptr0 + kk + 32);
        const uint4 b10 = *(const uint4*)(bptr1 + kk);
        const uint4 b11 = *(const uint4*)(bptr1 + kk + 32);
        __syncthreads();
        *(uint4*)sA0 = a00;
        *(uint4*)(sA0 + 32) = a01;
        *(uint4*)sA1 = a10;
        *(uint4*)(sA1 + 32) = a11;
        *(uint4*)sB0 = b00;
        *(uint4*)(sB0 + 32) = b01;
        *(uint4*)sB1 = b10;
        *(uint4*)(sB1 + 32) = b11;
        __syncthreads();
#pragma unroll
        for (int ko = 0; ko < 64; ko += 32) {
          short8 af[4], bf[4];
#pragma unroll
          for (int mt = 0; mt < 4; ++mt)
            af[mt] = *(const short8*)&sA[(wm * 64 + mt * 16 + m16) * 72 + ko +
                                         quad * 8];
#pragma unroll
          for (int nt = 0; nt < 4; ++nt)
            bf[nt] = *(const short8*)&sB[(wn * 64 + nt * 16 + m16) * 72 + ko +
                                         quad * 8];
#pragma unroll
          for (int mt = 0; mt < 4; ++mt)
#pragma unroll
            for (int nt = 0; nt < 4; ++nt)
              acc[mt][nt] = __builtin_amdgcn_mfma_f32_16x16x32_bf16(
                  af[mt], bf[nt], acc[mt][nt], 0, 0, 0);
        }
      }
      __syncthreads();
      short* sH = (short*)smem;  // [128][136] aliases sA|sB
#pragma unroll
      for (int nt = 0; nt < 4; ++nt) {
        const int cl = wn * 64 + nt * 16 + m16;
        const float bias = b1l[col0 + cl];
#pragma unroll
        for (int mt = 0; mt < 4; ++mt)
#pragma unroll
          for (int rg = 0; rg < 4; ++rg) {
            const int rl = wm * 64 + mt * 16 + quad * 4 + rg;
            sH[rl * 136 + cl] = (short)f2b(fmaxf(acc[mt][nt][rg] + bias, 0.f));
          }
      }
      __syncthreads();
      floatx4 c2[2] = {{0.f, 0.f, 0.f, 0.f}, {0.f, 0.f, 0.f, 0.f}};
#pragma unroll
      for (int kb = 0; kb < 4; ++kb) {
        const short8 bf2 =
            *(const short8*)&w2b[m16 * 256 + col0 + kb * 32 + quad * 8];
#pragma unroll
        for (int i = 0; i < 2; ++i) {
          const int mrow = (wave * 2 + i) * 16 + m16;
          const short8 af2 =
              *(const short8*)&sH[mrow * 136 + kb * 32 + quad * 8];
          c2[i] =
              __builtin_amdgcn_mfma_f32_16x16x32_bf16(af2, bf2, c2[i], 0, 0, 0);
        }
      }
#pragma unroll
      for (int i = 0; i < 2; ++i) {
        const int rbase = row0 + (wave * 2 + i) * 16 + quad * 4;
#pragma unroll
        for (int rg = 0; rg < 4; ++rg) {
          const int row = rbase + rg;
          if (row < NN) {
            if (m16 < 5)
              tt[(size_t)row * 16 + hf * 8 + m16] = c2[i][rg];
            else if (m16 < 10)
              rp[(size_t)hf * ((size_t)NN * 8) + (size_t)row * 8 + (m16 - 5)] =
                  c2[i][rg];
          }
        }
      }
      __syncthreads();
    }
  }
  gbar(ctr + 3);

  // ================= P5: layer-2 aggregate (16 lanes per node) ===============
  {
    const int l = t & 15;
    for (int node = bx * 16 + (t >> 4); node < NN; node += NB * 16) {
      const int beg = cur[node], end = cur[node + 1];
      float s0 = 0.f, s1 = 0.f, s2 = 0.f, s3 = 0.f, s4 = 0.f;
      for (int e = beg + l; e < end; e += 16) {
        const float* tp = tt + (size_t)esort[e] * 16;
        const float4 p0 = *(const float4*)tp;
        const float q0 = tp[4];
        const float4 p1 = *(const float4*)(tp + 8);
        const float q1 = tp[12];
        s0 += p0.x + p1.x;
        s1 += p0.y + p1.y;
        s2 += p0.z + p1.z;
        s3 += p0.w + p1.w;
        s4 += q0 + q1;
      }
#pragma unroll
      for (int m = 1; m < 16; m <<= 1) {
        s0 += __shfl_xor(s0, m, 64);
        s1 += __shfl_xor(s1, m, 64);
        s2 += __shfl_xor(s2, m, 64);
        s3 += __shfl_xor(s3, m, 64);
        s4 += __shfl_xor(s4, m, 64);
      }
      if (l == 0) {
        const float sc = inv[node];
        const float* r0 = rp + (size_t)node * 8;
        const float* r1 = rp + (size_t)NN * 8 + (size_t)node * 8;
        out[(size_t)node * D2 + 0] =
            fmaxf(s0 * sc + b2l[0] + r0[0] + r1[0], 0.f);
        out[(size_t)node * D2 + 1] =
            fmaxf(s1 * sc + b2l[1] + r0[1] + r1[1], 0.f);
        out[(size_t)node * D2 + 2] =
            fmaxf(s2 * sc + b2l[2] + r0[2] + r1[2], 0.f);
        out[(size_t)node * D2 + 3] =
            fmaxf(s3 * sc + b2l[3] + r0[3] + r1[3], 0.f);
        out[(size_t)node * D2 + 4] =
            fmaxf(s4 * sc + b2l[4] + r0[4] + r1[4], 0.f);
      }
    }
  }
}

extern "C" void kernel_launch(void* const* d_in, const int* in_sizes, int n_in,
                              void* d_out, int out_size, void* d_ws,
                              size_t ws_size, hipStream_t stream) {
  const float* x   = (const float*)d_in[0];
  const int*   ei  = (const int*)d_in[1];
  const int*   src = ei;
  const int*   dst = ei + NE;
  const float* W1l = (const float*)d_in[2];
  const float* b1l = (const float*)d_in[3];
  const float* W1r = (const float*)d_in[4];
  const float* W2l = (const float*)d_in[5];
  const float* b2l = (const float*)d_in[6];
  const float* W2r = (const float*)d_in[7];
  float* out = (float*)d_out;

  // workspace layout (4-byte units; ctr+gcur first -> single small memset)
  int*   ctr  = (int*)d_ws;                              // 8 (4 barriers)
  int*   gcur = ctr + 8;                                 // NBUK (196) pad 248
  unsigned short* ab  = (unsigned short*)(gcur + 248);   // NN*256 bf16
  unsigned short* wb  = ab + (size_t)NN * 256;           // 256*256 bf16
  unsigned short* w2b = wb + 256 * 256;                  // 16*256 bf16
  uint2* slab = (uint2*)(w2b + 16 * 256);                // NBUK*CAP pairs
  float* tt   = (float*)(slab + (size_t)NBUK * CAP);     // NN*16
  float* rp   = tt + (size_t)NN * 16;                    // 2*NN*8
  int*   cur  = (int*)(rp + (size_t)NN * 16);            // NN+1
  int*   esort = cur + NN + 1;                           // NE
  float* inv  = (float*)(esort + NE);                    // NN

  hipMemsetAsync(ctr, 0, 256 * sizeof(int), stream);  // ctr + gcur

  void* kargs[] = {(void*)&x,    (void*)&src, (void*)&dst,  (void*)&W1l,
                   (void*)&b1l,  (void*)&W1r, (void*)&W2l,  (void*)&b2l,
                   (void*)&W2r,  (void*)&ab,  (void*)&wb,   (void*)&w2b,
                   (void*)&tt,   (void*)&rp,  (void*)&slab, (void*)&gcur,
                   (void*)&cur,  (void*)&inv, (void*)&esort, (void*)&ctr,
                   (void*)&out};
  (void)kargs;
  k_all<<<NB, TPB, 0, stream>>>(x, src, dst, W1l, b1l, W1r, W2l, b2l, W2r, ab,
                                wb, w2b, tt, rp, slab, gcur, cur, inv, esort,
                                ctr, out);
}

// Round 13
// 182.101 us; speedup vs baseline: 3.3016x; 3.3016x over previous
//
#include <hip/hip_runtime.h>

static constexpr int NN = 50000;   // nodes
static constexpr int NE = 800000;  // edges
static constexpr int D0 = 128;     // in dim
static constexpr int D1 = 256;     // hidden
static constexpr int D2 = 5;       // out

// fused prepA grid partition (cvtx | cvtw1 | cvtw2 | bucketA)
static constexpr int XB = (NN * 32 + 255) / 256;   // 6250 cvtx blocks
static constexpr int WB = (D1 * 64) / 256;         // 64 cvtw blocks
static constexpr int PB = 4;                       // w2b convert blocks

// bucketed edge sort: BSZ pow2 so bucket = dst>>9
static constexpr int BSZ   = 512;                  // nodes per bucket
static constexpr int NBUK  = (NN + BSZ - 1) / BSZ; // 98
static constexpr int CAP   = 9216;   // slab cap (mean 8192, +11 sigma)
static constexpr int CB    = 400;    // chunk blocks in pass A
static constexpr int CHUNK = 2000;   // edges per chunk (CB*CHUNK == NE)

using short8  = __attribute__((ext_vector_type(8))) short;
using floatx4 = __attribute__((ext_vector_type(4))) float;

__device__ __forceinline__ unsigned short f2b(float f) {
  union { float f; unsigned u; } v; v.f = f;
  unsigned r = v.u + 0x7fffu + ((v.u >> 16) & 1u);  // RNE
  return (unsigned short)(r >> 16);
}
__device__ __forceinline__ float b2f(unsigned short s) {
  union { unsigned u; float f; } v; v.u = ((unsigned)s) << 16;
  return v.f;
}

// ---------------------- fused prep (cvtx|cvtw1|cvtw2) + bucketA, one dispatch
__global__ __launch_bounds__(256) void k_prepA(
    const float* __restrict__ x, unsigned short* __restrict__ ab,
    const float* __restrict__ W1l, const float* __restrict__ W1r,
    unsigned short* __restrict__ wb, const float* __restrict__ W2l,
    const float* __restrict__ W2r, unsigned short* __restrict__ w2b,
    const int* __restrict__ src, const int* __restrict__ dst,
    int* __restrict__ gcur, uint2* __restrict__ slab) {
  __shared__ int hist[128], bstart[128], gbase[128], hcur[128], sscan[128];
  __shared__ uint2 pairs[CHUNK];
  const int b = blockIdx.x, t = threadIdx.x;
  if (b < XB) {  // x -> bf16 into ab cols 128..255
    int idx = b * 256 + t;
    if (idx < NN * 32) {
      int node = idx >> 5, cg = idx & 31;
      float4 v = *(const float4*)(x + (size_t)node * D0 + cg * 4);
      ushort4 o;
      o.x = f2b(v.x); o.y = f2b(v.y); o.z = f2b(v.z); o.w = f2b(v.w);
      *(ushort4*)(ab + (size_t)node * 256 + 128 + cg * 4) = o;
    }
    return;
  }
  if (b < XB + WB) {  // [W1l|W1r] -> bf16 wb[col][256]
    int idx = (b - XB) * 256 + t;
    int c = idx >> 6, k = (idx & 63) * 4;
    const float* srcp = (k < 128) ? (W1l + (size_t)c * 128 + k)
                                  : (W1r + (size_t)c * 128 + (k - 128));
    float4 v = *(const float4*)srcp;
    ushort4 o;
    o.x = f2b(v.x); o.y = f2b(v.y); o.z = f2b(v.z); o.w = f2b(v.w);
    *(ushort4*)(wb + (size_t)c * 256 + k) = o;
    return;
  }
  if (b < XB + WB + PB) {  // W2l/W2r -> bf16 w2b[16][256], rows 10..15 = 0
    int idx = (b - XB - WB) * 256 + t;  // [0,1024)
    int n = idx >> 6, k = (idx & 63) * 4;
    float4 v = {0.f, 0.f, 0.f, 0.f};
    if (n < 5) v = *(const float4*)(W2l + (size_t)n * D1 + k);
    else if (n < 10) v = *(const float4*)(W2r + (size_t)(n - 5) * D1 + k);
    ushort4 o;
    o.x = f2b(v.x); o.y = f2b(v.y); o.z = f2b(v.z); o.w = f2b(v.w);
    *(ushort4*)(w2b + (size_t)n * 256 + k) = o;
    return;
  }
  // ---- bucketA: chunk -> LDS bucket-sort -> coalesced slab writes
  const int ba = b - (XB + WB + PB);
  const int e0 = ba * CHUNK;
  if (t < 128) hist[t] = 0;
  __syncthreads();
  for (int j = t; j < CHUNK; j += 256)
    atomicAdd(&hist[dst[e0 + j] >> 9], 1);
  __syncthreads();
  if (t < 128) sscan[t] = hist[t];
  __syncthreads();
  for (int dd = 1; dd < 128; dd <<= 1) {
    int u = (t >= dd && t < 128) ? sscan[t - dd] : 0;
    __syncthreads();
    if (t < 128) sscan[t] += u;
    __syncthreads();
  }
  if (t < 128) {
    bstart[t] = sscan[t] - hist[t];
    gbase[t] = (t < NBUK && hist[t] > 0) ? atomicAdd(&gcur[t], hist[t]) : 0;
    hcur[t] = 0;
  }
  __syncthreads();
  for (int j = t; j < CHUNK; j += 256) {
    const int s = src[e0 + j], d = dst[e0 + j];
    const int bk = d >> 9;
    const int pos = bstart[bk] + atomicAdd(&hcur[bk], 1);
    pairs[pos] = make_uint2((unsigned)s, (unsigned)d);
  }
  __syncthreads();
  for (int j = t; j < CHUNK; j += 256) {
    const uint2 pr = pairs[j];
    const int bk = (int)pr.y >> 9;
    slab[(size_t)bk * CAP + gbase[bk] + (j - bstart[bk])] = pr;
  }
}

// -------------------------------------------- pass BC: per-bucket CSR + scatter
__global__ __launch_bounds__(512) void k_bucketBC(
    const uint2* __restrict__ slab, const int* __restrict__ gcur,
    int* __restrict__ cur, float* __restrict__ inv,
    int* __restrict__ esort) {
  __shared__ int cnt[BSZ], s[BSZ], lcur[BSZ], g[128];
  const int b = blockIdx.x, t = threadIdx.x;
  const int n0 = b << 9;
  cnt[t] = 0;
  if (t < 128) g[t] = (t < NBUK) ? gcur[t] : 0;
  __syncthreads();
  for (int dd = 1; dd < 128; dd <<= 1) {
    int u = (t >= dd && t < 128) ? g[t - dd] : 0;
    __syncthreads();
    if (t < 128) g[t] += u;
    __syncthreads();
  }
  const int bbase = (b == 0) ? 0 : g[b - 1];
  const int cntE = gcur[b];
  const uint2* sp = slab + (size_t)b * CAP;
  for (int j = t; j < cntE; j += 512)
    atomicAdd(&cnt[(int)sp[j].y - n0], 1);
  __syncthreads();
  s[t] = cnt[t];
  __syncthreads();
  for (int dd = 1; dd < BSZ; dd <<= 1) {
    int u = (t >= dd) ? s[t - dd] : 0;
    __syncthreads();
    s[t] += u;
    __syncthreads();
  }
  const int start = bbase + (s[t] - cnt[t]);
  const int node = n0 + t;
  if (node < NN) {
    cur[node] = start;
    inv[node] = 1.0f / (float)max(cnt[t], 1);
  }
  lcur[t] = start;
  if (b == NBUK - 1 && t == 0) cur[NN] = NE;
  __syncthreads();
  for (int j = t; j < cntE; j += 512) {
    const uint2 pr = sp[j];
    const int p = atomicAdd(&lcur[(int)pr.y - n0], 1);
    esort[p] = (int)pr.x;
  }
}

// ---------------------------------------------------------------- aggregate 1
__global__ __launch_bounds__(256) void k_agg1(
    unsigned short* __restrict__ ab, const int* __restrict__ esort,
    const int* __restrict__ cur, const float* __restrict__ inv) {
  const int i = (blockIdx.x * 256 + threadIdx.x) >> 6;
  const int lane = threadIdx.x & 63;
  if (i >= NN) return;
  int e = cur[i];
  const int end = cur[i + 1];
  float a0 = 0.f, b0 = 0.f, a1 = 0.f, b1 = 0.f;
  float a2 = 0.f, b2 = 0.f, a3 = 0.f, b3 = 0.f;
  const unsigned short* xb = ab + 128 + lane * 2;
  while (e < end && (e & 3)) {
    const unsigned v = *(const unsigned*)(xb + (size_t)esort[e] * 256);
    a0 += b2f((unsigned short)v); b0 += b2f((unsigned short)(v >> 16));
    ++e;
  }
  for (; e + 7 < end; e += 8) {
    const int4 s0 = *(const int4*)(esort + e);
    const int4 s1 = *(const int4*)(esort + e + 4);
    const unsigned v0 = *(const unsigned*)(xb + (size_t)s0.x * 256);
    const unsigned v1 = *(const unsigned*)(xb + (size_t)s0.y * 256);
    const unsigned v2 = *(const unsigned*)(xb + (size_t)s0.z * 256);
    const unsigned v3 = *(const unsigned*)(xb + (size_t)s0.w * 256);
    const unsigned v4 = *(const unsigned*)(xb + (size_t)s1.x * 256);
    const unsigned v5 = *(const unsigned*)(xb + (size_t)s1.y * 256);
    const unsigned v6 = *(const unsigned*)(xb + (size_t)s1.z * 256);
    const unsigned v7 = *(const unsigned*)(xb + (size_t)s1.w * 256);
    a0 += b2f((unsigned short)v0); b0 += b2f((unsigned short)(v0 >> 16));
    a1 += b2f((unsigned short)v1); b1 += b2f((unsigned short)(v1 >> 16));
    a2 += b2f((unsigned short)v2); b2 += b2f((unsigned short)(v2 >> 16));
    a3 += b2f((unsigned short)v3); b3 += b2f((unsigned short)(v3 >> 16));
    a0 += b2f((unsigned short)v4); b0 += b2f((unsigned short)(v4 >> 16));
    a1 += b2f((unsigned short)v5); b1 += b2f((unsigned short)(v5 >> 16));
    a2 += b2f((unsigned short)v6); b2 += b2f((unsigned short)(v6 >> 16));
    a3 += b2f((unsigned short)v7); b3 += b2f((unsigned short)(v7 >> 16));
  }
  if (e + 3 < end) {
    const int4 s0 = *(const int4*)(esort + e);
    const unsigned v0 = *(const unsigned*)(xb + (size_t)s0.x * 256);
    const unsigned v1 = *(const unsigned*)(xb + (size_t)s0.y * 256);
    const unsigned v2 = *(const unsigned*)(xb + (size_t)s0.z * 256);
    const unsigned v3 = *(const unsigned*)(xb + (size_t)s0.w * 256);
    a0 += b2f((unsigned short)v0); b0 += b2f((unsigned short)(v0 >> 16));
    a1 += b2f((unsigned short)v1); b1 += b2f((unsigned short)(v1 >> 16));
    a2 += b2f((unsigned short)v2); b2 += b2f((unsigned short)(v2 >> 16));
    a3 += b2f((unsigned short)v3); b3 += b2f((unsigned short)(v3 >> 16));
    e += 4;
  }
  for (; e < end; ++e) {
    const unsigned v = *(const unsigned*)(xb + (size_t)esort[e] * 256);
    a0 += b2f((unsigned short)v); b0 += b2f((unsigned short)(v >> 16));
  }
  const float sc = inv[i];
  const float sa = (a0 + a1) + (a2 + a3);
  const float sb = (b0 + b1) + (b2 + b3);
  const unsigned out =
      ((unsigned)f2b(sb * sc) << 16) | (unsigned)f2b(sa * sc);
  *(unsigned*)(ab + (size_t)i * 256 + lane * 2) = out;
}

// ------------------------------------- GEMM 1 + fused layer-2 linear (MFMA)
// 128x128 tile, BK=64, K-loop software-pipelined: next chunk's global loads
// issued right after the LDS-store barrier so they overlap the 32 MFMAs.
__global__ __launch_bounds__(256) void k_gemm1f(
    const unsigned short* __restrict__ ab, const unsigned short* __restrict__ wb,
    const unsigned short* __restrict__ w2b, const float* __restrict__ b1l,
    float* __restrict__ tt, float* __restrict__ rp) {
  __shared__ short sAB[2 * 128 * 72];  // sA | sB, later reused as sH[128][136]
  short* sA = sAB;
  short* sB = sAB + 128 * 72;
  const int tid = threadIdx.x;
  const int row0 = blockIdx.y * 128;
  const int hf = blockIdx.x;       // col half
  const int col0 = hf * 128;
  const int wave = tid >> 6, lane = tid & 63;
  const int quad = lane >> 4, m16 = lane & 15;
  const int wm = wave & 1, wn = wave >> 1;
  const int lr = tid >> 2;
  const int lk = (tid & 3) * 8;

  floatx4 acc[4][4];
#pragma unroll
  for (int a = 0; a < 4; ++a)
#pragma unroll
    for (int b = 0; b < 4; ++b) acc[a][b] = {0.f, 0.f, 0.f, 0.f};

  const int gr0 = row0 + lr, gr1 = row0 + lr + 64;
  const bool ok0 = gr0 < NN, ok1 = gr1 < NN;
  const unsigned short* aptr0 = ab + (size_t)gr0 * 256 + lk;
  const unsigned short* aptr1 = ab + (size_t)gr1 * 256 + lk;
  const unsigned short* bptr0 = wb + (size_t)(col0 + lr) * 256 + lk;
  const unsigned short* bptr1 = wb + (size_t)(col0 + lr + 64) * 256 + lk;
  short* sA0 = &sA[lr * 72 + lk];
  short* sA1 = &sA[(lr + 64) * 72 + lk];
  short* sB0 = &sB[lr * 72 + lk];
  short* sB1 = &sB[(lr + 64) * 72 + lk];
  const uint4 zz = make_uint4(0, 0, 0, 0);

  // preload chunk 0
  uint4 a00 = ok0 ? *(const uint4*)(aptr0) : zz;
  uint4 a01 = ok0 ? *(const uint4*)(aptr0 + 32) : zz;
  uint4 a10 = ok1 ? *(const uint4*)(aptr1) : zz;
  uint4 a11 = ok1 ? *(const uint4*)(aptr1 + 32) : zz;
  uint4 b00 = *(const uint4*)(bptr0);
  uint4 b01 = *(const uint4*)(bptr0 + 32);
  uint4 b10 = *(const uint4*)(bptr1);
  uint4 b11 = *(const uint4*)(bptr1 + 32);

  for (int kk = 0; kk < 256; kk += 64) {
    __syncthreads();  // previous iteration's ds_reads done
    *(uint4*)sA0 = a00;
    *(uint4*)(sA0 + 32) = a01;
    *(uint4*)sA1 = a10;
    *(uint4*)(sA1 + 32) = a11;
    *(uint4*)sB0 = b00;
    *(uint4*)(sB0 + 32) = b01;
    *(uint4*)sB1 = b10;
    *(uint4*)(sB1 + 32) = b11;
    __syncthreads();
    if (kk < 192) {  // prefetch next chunk; overlaps the MFMAs below
      const int kn = kk + 64;
      a00 = ok0 ? *(const uint4*)(aptr0 + kn) : zz;
      a01 = ok0 ? *(const uint4*)(aptr0 + kn + 32) : zz;
      a10 = ok1 ? *(const uint4*)(aptr1 + kn) : zz;
      a11 = ok1 ? *(const uint4*)(aptr1 + kn + 32) : zz;
      b00 = *(const uint4*)(bptr0 + kn);
      b01 = *(const uint4*)(bptr0 + kn + 32);
      b10 = *(const uint4*)(bptr1 + kn);
      b11 = *(const uint4*)(bptr1 + kn + 32);
    }
#pragma unroll
    for (int ko = 0; ko < 64; ko += 32) {
      short8 af[4], bf[4];
#pragma unroll
      for (int mt = 0; mt < 4; ++mt)
        af[mt] =
            *(const short8*)&sA[(wm * 64 + mt * 16 + m16) * 72 + ko + quad * 8];
#pragma unroll
      for (int nt = 0; nt < 4; ++nt)
        bf[nt] =
            *(const short8*)&sB[(wn * 64 + nt * 16 + m16) * 72 + ko + quad * 8];
#pragma unroll
      for (int mt = 0; mt < 4; ++mt)
#pragma unroll
        for (int nt = 0; nt < 4; ++nt)
          acc[mt][nt] = __builtin_amdgcn_mfma_f32_16x16x32_bf16(
              af[mt], bf[nt], acc[mt][nt], 0, 0, 0);
    }
  }

  // ---- epilogue: h=relu(acc+bias) -> sH bf16; then t/r = h @ w2b^T
  __syncthreads();  // K-loop ds_reads done; safe to overwrite
  short* sH = sAB;  // [128][136]
#pragma unroll
  for (int nt = 0; nt < 4; ++nt) {
    const int cl = wn * 64 + nt * 16 + m16;
    const float bias = b1l[col0 + cl];
#pragma unroll
    for (int mt = 0; mt < 4; ++mt)
#pragma unroll
      for (int rg = 0; rg < 4; ++rg) {
        const int rl = wm * 64 + mt * 16 + quad * 4 + rg;
        sH[rl * 136 + cl] = (short)f2b(fmaxf(acc[mt][nt][rg] + bias, 0.f));
      }
  }
  __syncthreads();
  floatx4 c2[2] = {{0.f, 0.f, 0.f, 0.f}, {0.f, 0.f, 0.f, 0.f}};
#pragma unroll
  for (int kb = 0; kb < 4; ++kb) {
    const short8 bf2 =
        *(const short8*)&w2b[m16 * 256 + col0 + kb * 32 + quad * 8];
#pragma unroll
    for (int i = 0; i < 2; ++i) {
      const int mrow = (wave * 2 + i) * 16 + m16;
      const short8 af2 = *(const short8*)&sH[mrow * 136 + kb * 32 + quad * 8];
      c2[i] = __builtin_amdgcn_mfma_f32_16x16x32_bf16(af2, bf2, c2[i], 0, 0, 0);
    }
  }
  // C layout: col(n)=m16, row=quad*4+rg. n<5 -> t partial, 5..9 -> r partial.
#pragma unroll
  for (int i = 0; i < 2; ++i) {
    const int rbase = row0 + (wave * 2 + i) * 16 + quad * 4;
#pragma unroll
    for (int rg = 0; rg < 4; ++rg) {
      const int row = rbase + rg;
      if (row < NN) {
        if (m16 < 5)
          tt[(size_t)row * 16 + hf * 8 + m16] = c2[i][rg];
        else if (m16 < 10)
          rp[(size_t)hf * ((size_t)NN * 8) + (size_t)row * 8 + (m16 - 5)] =
              c2[i][rg];
      }
    }
  }
}

// ------------------------------------- layer-2 aggregate: 16 lanes per node
__global__ __launch_bounds__(256) void k_layer2(
    const float* __restrict__ tt, const float* __restrict__ rp,
    const int* __restrict__ esort, const int* __restrict__ cur,
    const float* __restrict__ inv, const float* __restrict__ b2l,
    float* __restrict__ out) {
  const int node = blockIdx.x * 16 + (threadIdx.x >> 4);
  const int l = threadIdx.x & 15;
  if (node >= NN) return;
  const int beg = cur[node], end = cur[node + 1];
  float s0 = 0.f, s1 = 0.f, s2 = 0.f, s3 = 0.f, s4 = 0.f;
  for (int e = beg + l; e < end; e += 16) {
    const float* tp = tt + (size_t)esort[e] * 16;
    const float4 p0 = *(const float4*)tp;
    const float q0 = tp[4];
    const float4 p1 = *(const float4*)(tp + 8);
    const float q1 = tp[12];
    s0 += p0.x + p1.x;
    s1 += p0.y + p1.y;
    s2 += p0.z + p1.z;
    s3 += p0.w + p1.w;
    s4 += q0 + q1;
  }
#pragma unroll
  for (int m = 1; m < 16; m <<= 1) {
    s0 += __shfl_xor(s0, m, 64);
    s1 += __shfl_xor(s1, m, 64);
    s2 += __shfl_xor(s2, m, 64);
    s3 += __shfl_xor(s3, m, 64);
    s4 += __shfl_xor(s4, m, 64);
  }
  if (l == 0) {
    const float sc = inv[node];
    const float* r0 = rp + (size_t)node * 8;
    const float* r1 = rp + (size_t)NN * 8 + (size_t)node * 8;
    out[(size_t)node * D2 + 0] = fmaxf(s0 * sc + b2l[0] + r0[0] + r1[0], 0.f);
    out[(size_t)node * D2 + 1] = fmaxf(s1 * sc + b2l[1] + r0[1] + r1[1], 0.f);
    out[(size_t)node * D2 + 2] = fmaxf(s2 * sc + b2l[2] + r0[2] + r1[2], 0.f);
    out[(size_t)node * D2 + 3] = fmaxf(s3 * sc + b2l[3] + r0[3] + r1[3], 0.f);
    out[(size_t)node * D2 + 4] = fmaxf(s4 * sc + b2l[4] + r0[4] + r1[4], 0.f);
  }
}

extern "C" void kernel_launch(void* const* d_in, const int* in_sizes, int n_in,
                              void* d_out, int out_size, void* d_ws,
                              size_t ws_size, hipStream_t stream) {
  const float* x   = (const float*)d_in[0];
  const int*   ei  = (const int*)d_in[1];
  const int*   src = ei;
  const int*   dst = ei + NE;
  const float* W1l = (const float*)d_in[2];
  const float* b1l = (const float*)d_in[3];
  const float* W1r = (const float*)d_in[4];
  const float* W2l = (const float*)d_in[5];
  const float* b2l = (const float*)d_in[6];
  const float* W2r = (const float*)d_in[7];
  float* out = (float*)d_out;

  // workspace layout: big aligned arrays first (16B-aligned offsets)
  unsigned short* ab  = (unsigned short*)d_ws;          // NN*256 bf16
  unsigned short* wb  = ab + (size_t)NN * 256;          // 256*256 bf16
  unsigned short* w2b = wb + 256 * 256;                 // 16*256 bf16
  float* tt   = (float*)(w2b + 16 * 256);               // NN*16 (t interleaved)
  float* rp   = tt + (size_t)NN * 16;                   // 2 * NN*8 (r partials)
  uint2* slab = (uint2*)(rp + (size_t)NN * 16);         // NBUK*CAP pairs
  int*   gcur = (int*)(slab + (size_t)NBUK * CAP);      // 128
  int*   cur  = gcur + 128;                             // NN+1
  int*   esort = cur + NN + 1;                          // NE
  float* inv  = (float*)(esort + NE);                   // NN

  hipMemsetAsync(gcur, 0, 128 * sizeof(int), stream);

  k_prepA<<<XB + WB + PB + CB, 256, 0, stream>>>(x, ab, W1l, W1r, wb, W2l, W2r,
                                                 w2b, src, dst, gcur, slab);
  k_bucketBC<<<NBUK, 512, 0, stream>>>(slab, gcur, cur, inv, esort);
  k_agg1<<<(NN * 64 + 255) / 256, 256, 0, stream>>>(ab, esort, cur, inv);
  dim3 g1(2, (NN + 127) / 128);
  k_gemm1f<<<g1, 256, 0, stream>>>(ab, wb, w2b, b1l, tt, rp);
  k_layer2<<<(NN + 15) / 16, 256, 0, stream>>>(tt, rp, esort, cur, inv, b2l,
                                               out);
}